// Round 1
// 72.754 us; speedup vs baseline: 1.0196x; 1.0196x over previous
//
#include <hip/hip_runtime.h>
#include <math.h>

// KAN layer forward, MI355X (gfx950).
// batch=2048, n_in=64, n_out=64, n=4096, 10 knots (all rows identical), K=3.
// Outputs (FLOAT32, concat in d_out): y (2048,64) then spl_reg (64,64).
// Round 7: occupancy + LDS-vectorization pass.
//  - grid 256 -> 512 blocks: each batch-chunk's j-range split across 2 blocks
//    (half = blockIdx&1 covers j in [half*2048, half*2048+2048)). 2 blocks/CU
//    -> 4 waves/SIMD (was 2): latency hiding for the serial shuffle chains.
//  - basis staged as 2x float4 per thread (ds_write_b128/ds_read_b128) instead
//    of 7 scalar floats (was 7 writes + 56 reads of b32 per thread).
//  - y epilogue staged in LDS -> coalesced 128B stores (was 8-lane scatter).
//  - kan_reduce re-gridded 64 -> 256 blocks (full CU coverage).

#define BATCHN 2048
#define NI     64
#define NO     64
#define NTOTAL 4096
#define BB     8                    // batches per chunk
#define NCHUNK (BATCHN / BB)        // 256 chunks; grid = 2*NCHUNK
#define TPB    512

// 6 cubic B-spline bases + silu for one x (verified rounds 3/4/6).
__device__ __forceinline__ void eval_basis6(float xv,
                                            const float* tt,
                                            const float* inv1,
                                            const float* inv2,
                                            const float* inv3,
                                            float* bout, float* silu)
{
    float c[10], d[10];
#pragma unroll
    for (int m = 0; m < 10; ++m) {
        c[m] = (xv >= tt[m]) ? 1.0f : 0.0f;
        d[m] = xv - tt[m];
    }
    float b[9], w[9];
#pragma unroll
    for (int m = 0; m < 9; ++m) b[m] = c[m] - c[m + 1];
#pragma unroll
    for (int m = 0; m < 9; ++m) w[m] = b[m] * inv1[m];
#pragma unroll
    for (int m = 0; m < 8; ++m) b[m] = d[m] * w[m] - d[m + 2] * w[m + 1];
#pragma unroll
    for (int m = 0; m < 8; ++m) w[m] = b[m] * inv2[m];
#pragma unroll
    for (int m = 0; m < 7; ++m) b[m] = d[m] * w[m] - d[m + 3] * w[m + 1];
#pragma unroll
    for (int m = 0; m < 7; ++m) w[m] = b[m] * inv3[m];
#pragma unroll
    for (int m = 0; m < 6; ++m) bout[m] = d[m] * w[m] - d[m + 4] * w[m + 1];
    *silu = xv / (1.0f + expf(-xv));
}

__global__ __launch_bounds__(TPB, 4) void kan_main(
    const float* __restrict__ x, const float* __restrict__ cb,
    const float* __restrict__ c_spl, const float* __restrict__ c_res,
    const float* __restrict__ grid, float* __restrict__ y,
    float* __restrict__ regpart, int write_part)
{
    __shared__ float4 sB4[2][TPB];    // [0]=B0..B3, [1]=B4,B5,silu,pad
    __shared__ float  sY[8][33];      // +1 pad col: conflict-free scatter write
    const int t    = threadIdx.x;          // 0..511
    const int lane = t & 63;               // = i
    const int wv   = t >> 6;               // 0..7
    const int bchunk = blockIdx.x >> 1;    // 0..255
    const int half   = blockIdx.x & 1;     // which j-half this block owns
    const int bbase  = bchunk * BB;

    float tt[10];
#pragma unroll
    for (int m = 0; m < 10; ++m) tt[m] = grid[m];
    float inv1[9], inv2[8], inv3[7];
#pragma unroll
    for (int m = 0; m < 9; ++m) inv1[m] = 1.0f / (tt[m + 1] - tt[m]);
#pragma unroll
    for (int m = 0; m < 8; ++m) inv2[m] = 1.0f / (tt[m + 2] - tt[m]);
#pragma unroll
    for (int m = 0; m < 7; ++m) inv3[m] = 1.0f / (tt[m + 3] - tt[m]);

    // Phase 1: 512 basis evals, one per thread (duplicated across the two
    // j-half sibling blocks -- ~130 VALU, cheap). Coalesced x reads.
    {
        const float xv = x[bbase * NI + t];      // t = bb*64 + i
        float bo[6], sl;
        eval_basis6(xv, tt, inv1, inv2, inv3, bo, &sl);
        sB4[0][t] = make_float4(bo[0], bo[1], bo[2], bo[3]);
        sB4[1][t] = make_float4(bo[4], bo[5], sl, 0.0f);
    }
    __syncthreads();

    // Phase 2: my (i=lane, bb=0..7) basis -> 56 registers via 16 ds_read_b128
    float B0[8], B1[8], B2[8], B3[8], B4[8], B5[8], SL[8];
#pragma unroll
    for (int bb = 0; bb < 8; ++bb) {
        const int p = bb * 64 + lane;          // lane-consecutive float4s
        const float4 a = sB4[0][p];
        const float4 b = sB4[1][p];
        B0[bb] = a.x; B1[bb] = a.y; B2[bb] = a.z; B3[bb] = a.w;
        B4[bb] = b.x; B5[bb] = b.y; SL[bb] = b.z;
    }

    const bool p0 = (lane & 1), p1 = (lane & 2), p2 = (lane & 4);
#pragma unroll 2
    for (int jj4 = 0; jj4 < 4; ++jj4) {
        const int jj = (half << 2) + jj4;      // 0..7 across sibling blocks
        const int j  = jj * TPB + t;           // o = j>>6 = jj*8 + wv, i = lane
        const float* cbp = cb + j * 6;         // 24B stride, 8B aligned
        const float2 c01 = *(const float2*)(cbp);
        const float2 c23 = *(const float2*)(cbp + 2);
        const float2 c45 = *(const float2*)(cbp + 4);
        const float cs = c_spl[j];
        const float cr = c_res[j];

        float v[8];
        float rabs = 0.0f;
#pragma unroll
        for (int bb = 0; bb < 8; ++bb) {
            float s = c01.x * B0[bb];
            s = fmaf(c01.y, B1[bb], s);
            s = fmaf(c23.x, B2[bb], s);
            s = fmaf(c23.y, B3[bb], s);
            s = fmaf(c45.x, B4[bb], s);
            s = fmaf(c45.y, B5[bb], s);
            rabs += fabsf(s);
            v[bb] = fmaf(cs, s, cr * SL[bb]);
        }
        if (write_part) regpart[bchunk * NTOTAL + j] = rabs;  // coalesced

        // packed butterfly: 8 batch-sums over 64 lanes (i) in 10 shuffles.
        // After the 3 pack steps, v[0] on lane L holds batch index
        // bbL = 4*(L&1) + 2*((L>>1)&1) + ((L>>2)&1), summed per 8-lane group.
#pragma unroll
        for (int r = 0; r < 4; ++r) {
            float send = p0 ? v[r] : v[r + 4];
            float recv = __shfl_xor(send, 1, 64);
            float keep = p0 ? v[r + 4] : v[r];
            v[r] = keep + recv;
        }
#pragma unroll
        for (int r = 0; r < 2; ++r) {
            float send = p1 ? v[r] : v[r + 2];
            float recv = __shfl_xor(send, 2, 64);
            float keep = p1 ? v[r + 2] : v[r];
            v[r] = keep + recv;
        }
        {
            float send = p2 ? v[0] : v[1];
            float recv = __shfl_xor(send, 4, 64);
            float keep = p2 ? v[1] : v[0];
            v[0] = keep + recv;
        }
        v[0] += __shfl_xor(v[0], 8, 64);
        v[0] += __shfl_xor(v[0], 16, 64);
        v[0] += __shfl_xor(v[0], 32, 64);
        if (lane < 8) {
            const int bbL = ((lane & 1) << 2) | (lane & 2) | ((lane >> 2) & 1);
            // o within this block's half = jj4*8 + wv, in [0,32)
            sY[bbL][(jj4 << 3) + wv] = v[0] * (1.0f / 64.0f);
        }
    }
    __syncthreads();

    // Coalesced y epilogue: this block owns o in [half*32, half*32+32)
    if (t < 256) {
        const int bbL = t >> 5, oo = t & 31;
        y[(bbase + bbL) * NO + (half << 5) + oo] = sY[bbL][oo];
    }
}

// Reduce: spl_reg[q] = (sum_chunk part[chunk][q]) / 2048 / (t9 - t0 + 1e-5)
// 256 blocks x 256 threads: block owns 16 q columns, 16 threads per column
// each sum 16 chunks.
__global__ __launch_bounds__(256) void kan_reduce(
    const float* __restrict__ regpart, const float* __restrict__ grid,
    float* __restrict__ outreg)
{
    __shared__ float sR[16][17];
    const int t  = threadIdx.x;
    const int qo = t & 15, gs = t >> 4;
    const int q  = blockIdx.x * 16 + qo;
    float s = 0.0f;
#pragma unroll
    for (int g = gs * 16; g < gs * 16 + 16; ++g) s += regpart[g * NTOTAL + q];
    sR[gs][qo] = s;
    __syncthreads();
    if (t < 16) {
        float tot = 0.0f;
#pragma unroll
        for (int g2 = 0; g2 < 16; ++g2) tot += sR[g2][t];
        const int jq = blockIdx.x * 16 + t;
        const float norm = grid[jq * 10 + 9] - grid[jq * 10] + 1e-5f;
        outreg[jq] = (tot * (1.0f / (float)BATCHN)) / norm;
    }
}

// Fallback (ws too small): round-3 standalone spl_reg kernel (known-good).
__global__ __launch_bounds__(256) void kan_reg_standalone(
    const float* __restrict__ x, const float* __restrict__ cb,
    const float* __restrict__ grid, float* __restrict__ outreg)
{
    __shared__ float sB2[6][256];
    __shared__ float sR[256];
    const int t = threadIdx.x;
    const int i = blockIdx.x;

    float tt[10];
#pragma unroll
    for (int m = 0; m < 10; ++m) tt[m] = grid[m];
    float inv1[9], inv2[8], inv3[7];
#pragma unroll
    for (int m = 0; m < 9; ++m) inv1[m] = 1.0f / (tt[m + 1] - tt[m]);
#pragma unroll
    for (int m = 0; m < 8; ++m) inv2[m] = 1.0f / (tt[m + 2] - tt[m]);
#pragma unroll
    for (int m = 0; m < 7; ++m) inv3[m] = 1.0f / (tt[m + 3] - tt[m]);

    const int o = t >> 2;
    const int q = t & 3;
    const int j = o * NI + i;
    const float c0 = cb[j * 6 + 0], c1 = cb[j * 6 + 1], c2 = cb[j * 6 + 2];
    const float c3 = cb[j * 6 + 3], c4 = cb[j * 6 + 4], c5 = cb[j * 6 + 5];

    float acc = 0.0f;
    for (int tile = 0; tile < 8; ++tile) {
        const float xv = x[(tile * 256 + t) * NI + i];
        float bo[6], sl;
        eval_basis6(xv, tt, inv1, inv2, inv3, bo, &sl);
        __syncthreads();
#pragma unroll
        for (int m = 0; m < 6; ++m) sB2[m][t] = bo[m];
        __syncthreads();
        for (int bi = 0; bi < 64; ++bi) {
            const int b = q * 64 + ((bi + q * 8) & 63);
            float s = c0 * sB2[0][b];
            s = fmaf(c1, sB2[1][b], s);
            s = fmaf(c2, sB2[2][b], s);
            s = fmaf(c3, sB2[3][b], s);
            s = fmaf(c4, sB2[4][b], s);
            s = fmaf(c5, sB2[5][b], s);
            acc += fabsf(s);
        }
    }
    sR[t] = acc;
    __syncthreads();
    if (t < 64) {
        const float s = sR[t * 4 + 0] + sR[t * 4 + 1] + sR[t * 4 + 2] + sR[t * 4 + 3];
        const int jj = t * NI + i;
        const float norm = grid[jj * 10 + 9] - grid[jj * 10] + 1e-5f;
        outreg[jj] = (s * (1.0f / (float)BATCHN)) / norm;
    }
}

extern "C" void kernel_launch(void* const* d_in, const int* in_sizes, int n_in,
                              void* d_out, int out_size, void* d_ws, size_t ws_size,
                              hipStream_t stream) {
    (void)in_sizes; (void)n_in; (void)out_size;
    const float* x    = (const float*)d_in[0];
    const float* cb   = (const float*)d_in[1];
    const float* cspl = (const float*)d_in[2];
    const float* cres = (const float*)d_in[3];
    const float* grid = (const float*)d_in[4];
    float* y      = (float*)d_out;
    float* outreg = y + BATCHN * NO;

    const size_t needed = (size_t)NCHUNK * NTOTAL * sizeof(float);   // 4 MiB
    if (ws_size >= needed) {
        float* part = (float*)d_ws;
        kan_main<<<NCHUNK * 2, TPB, 0, stream>>>(x, cb, cspl, cres, grid, y, part, 1);
        kan_reduce<<<NTOTAL / 16, 256, 0, stream>>>(part, grid, outreg);
    } else {
        kan_main<<<NCHUNK * 2, TPB, 0, stream>>>(x, cb, cspl, cres, grid, y,
                                                 (float*)d_ws, 0);
        kan_reg_standalone<<<NI, 256, 0, stream>>>(x, cb, grid, outreg);
    }
}

// Round 2
// 72.156 us; speedup vs baseline: 1.0281x; 1.0083x over previous
//
#include <hip/hip_runtime.h>
#include <math.h>

// KAN layer forward, MI355X (gfx950).
// batch=2048, n_in=64, n_out=64, n=4096, 10 knots (all rows identical), K=3.
// Outputs (FLOAT32, concat in d_out): y (2048,64) then spl_reg (64,64).
// Round 8: VMEM latency-hiding pass. Round 7 (+occupancy, b128 LDS) moved
// total only -1.4us -> kan_main is already ~6-9us; timed region is dominated
// by the harness's 256MiB ws-poison fill (41us @ 82% HBM peak, immovable) +
// restore dispatches. This round hoists ALL global loads (x, then all 4 jj
// coefficient sets) to the top of kan_main, ahead of the rcp chain / basis
// eval / phase-2 LDS reads, so the ~500-cyc VMEM latencies overlap VALU/DS
// work instead of sitting on the critical path. Peak VGPR ~106 < 128 cap
// from __launch_bounds__(512,4), so occupancy stays 2 blocks/CU.

#define BATCHN 2048
#define NI     64
#define NO     64
#define NTOTAL 4096
#define BB     8                    // batches per chunk
#define NCHUNK (BATCHN / BB)        // 256 chunks; grid = 2*NCHUNK
#define TPB    512

// 6 cubic B-spline bases + silu for one x (verified rounds 3/4/6/7).
__device__ __forceinline__ void eval_basis6(float xv,
                                            const float* tt,
                                            const float* inv1,
                                            const float* inv2,
                                            const float* inv3,
                                            float* bout, float* silu)
{
    float c[10], d[10];
#pragma unroll
    for (int m = 0; m < 10; ++m) {
        c[m] = (xv >= tt[m]) ? 1.0f : 0.0f;
        d[m] = xv - tt[m];
    }
    float b[9], w[9];
#pragma unroll
    for (int m = 0; m < 9; ++m) b[m] = c[m] - c[m + 1];
#pragma unroll
    for (int m = 0; m < 9; ++m) w[m] = b[m] * inv1[m];
#pragma unroll
    for (int m = 0; m < 8; ++m) b[m] = d[m] * w[m] - d[m + 2] * w[m + 1];
#pragma unroll
    for (int m = 0; m < 8; ++m) w[m] = b[m] * inv2[m];
#pragma unroll
    for (int m = 0; m < 7; ++m) b[m] = d[m] * w[m] - d[m + 3] * w[m + 1];
#pragma unroll
    for (int m = 0; m < 7; ++m) w[m] = b[m] * inv3[m];
#pragma unroll
    for (int m = 0; m < 6; ++m) bout[m] = d[m] * w[m] - d[m + 4] * w[m + 1];
    *silu = xv / (1.0f + expf(-xv));
}

__global__ __launch_bounds__(TPB, 4) void kan_main(
    const float* __restrict__ x, const float* __restrict__ cb,
    const float* __restrict__ c_spl, const float* __restrict__ c_res,
    const float* __restrict__ grid, float* __restrict__ y,
    float* __restrict__ regpart, int write_part)
{
    __shared__ float4 sB4[2][TPB];    // [0]=B0..B3, [1]=B4,B5,silu,pad
    __shared__ float  sY[8][33];      // +1 pad col: conflict-free scatter write
    const int t    = threadIdx.x;          // 0..511
    const int lane = t & 63;               // = i
    const int wv   = t >> 6;               // 0..7
    const int bchunk = blockIdx.x >> 1;    // 0..255
    const int half   = blockIdx.x & 1;     // which j-half this block owns
    const int bbase  = bchunk * BB;

    // ---- Issue ALL global loads up front (latency hides under the rcp
    // chain, basis eval and phase-2 LDS reads). x first (needed earliest).
    const float xv = x[bbase * NI + t];      // t = bb*64 + i, coalesced

    float2 c01[4], c23[4], c45[4];
    float  cs[4], cr[4];
#pragma unroll
    for (int q = 0; q < 4; ++q) {
        const int j = (half * 4 + q) * TPB + t;   // this block's 4 j-tiles
        const float* cbp = cb + (size_t)j * 6;    // 24B stride, 8B aligned
        c01[q] = *(const float2*)(cbp);
        c23[q] = *(const float2*)(cbp + 2);
        c45[q] = *(const float2*)(cbp + 4);
        cs[q]  = c_spl[j];
        cr[q]  = c_res[j];
    }

    float tt[10];
#pragma unroll
    for (int m = 0; m < 10; ++m) tt[m] = grid[m];
    float inv1[9], inv2[8], inv3[7];
#pragma unroll
    for (int m = 0; m < 9; ++m) inv1[m] = 1.0f / (tt[m + 1] - tt[m]);
#pragma unroll
    for (int m = 0; m < 8; ++m) inv2[m] = 1.0f / (tt[m + 2] - tt[m]);
#pragma unroll
    for (int m = 0; m < 7; ++m) inv3[m] = 1.0f / (tt[m + 3] - tt[m]);

    // Phase 1: 512 basis evals, one per thread (duplicated across the two
    // j-half sibling blocks -- ~130 VALU, cheap).
    {
        float bo[6], sl;
        eval_basis6(xv, tt, inv1, inv2, inv3, bo, &sl);
        sB4[0][t] = make_float4(bo[0], bo[1], bo[2], bo[3]);
        sB4[1][t] = make_float4(bo[4], bo[5], sl, 0.0f);
    }
    __syncthreads();

    // Phase 2: my (i=lane, bb=0..7) basis -> 56 registers via 16 ds_read_b128
    float B0[8], B1[8], B2[8], B3[8], B4[8], B5[8], SL[8];
#pragma unroll
    for (int bb = 0; bb < 8; ++bb) {
        const int p = bb * 64 + lane;          // lane-consecutive float4s
        const float4 a = sB4[0][p];
        const float4 b = sB4[1][p];
        B0[bb] = a.x; B1[bb] = a.y; B2[bb] = a.z; B3[bb] = a.w;
        B4[bb] = b.x; B5[bb] = b.y; SL[bb] = b.z;
    }

    const bool p0 = (lane & 1), p1 = (lane & 2), p2 = (lane & 4);
#pragma unroll
    for (int q = 0; q < 4; ++q) {
        const int jj = half * 4 + q;           // 0..7 across sibling blocks
        const int j  = jj * TPB + t;           // o = j>>6 = jj*8 + wv, i = lane

        float v[8];
        float rabs = 0.0f;
#pragma unroll
        for (int bb = 0; bb < 8; ++bb) {
            float s = c01[q].x * B0[bb];
            s = fmaf(c01[q].y, B1[bb], s);
            s = fmaf(c23[q].x, B2[bb], s);
            s = fmaf(c23[q].y, B3[bb], s);
            s = fmaf(c45[q].x, B4[bb], s);
            s = fmaf(c45[q].y, B5[bb], s);
            rabs += fabsf(s);
            v[bb] = fmaf(cs[q], s, cr[q] * SL[bb]);
        }
        if (write_part) regpart[bchunk * NTOTAL + j] = rabs;  // coalesced

        // packed butterfly: 8 batch-sums over 64 lanes (i) in 10 shuffles.
        // After the 3 pack steps, v[0] on lane L holds batch index
        // bbL = 4*(L&1) + 2*((L>>1)&1) + ((L>>2)&1), summed per 8-lane group.
#pragma unroll
        for (int r = 0; r < 4; ++r) {
            float send = p0 ? v[r] : v[r + 4];
            float recv = __shfl_xor(send, 1, 64);
            float keep = p0 ? v[r + 4] : v[r];
            v[r] = keep + recv;
        }
#pragma unroll
        for (int r = 0; r < 2; ++r) {
            float send = p1 ? v[r] : v[r + 2];
            float recv = __shfl_xor(send, 2, 64);
            float keep = p1 ? v[r + 2] : v[r];
            v[r] = keep + recv;
        }
        {
            float send = p2 ? v[0] : v[1];
            float recv = __shfl_xor(send, 4, 64);
            float keep = p2 ? v[1] : v[0];
            v[0] = keep + recv;
        }
        v[0] += __shfl_xor(v[0], 8, 64);
        v[0] += __shfl_xor(v[0], 16, 64);
        v[0] += __shfl_xor(v[0], 32, 64);
        if (lane < 8) {
            const int bbL = ((lane & 1) << 2) | (lane & 2) | ((lane >> 2) & 1);
            // o within this block's half = q*8 + wv, in [0,32)
            sY[bbL][(q << 3) + wv] = v[0] * (1.0f / 64.0f);
        }
    }
    __syncthreads();

    // Coalesced y epilogue: this block owns o in [half*32, half*32+32)
    if (t < 256) {
        const int bbL = t >> 5, oo = t & 31;
        y[(bbase + bbL) * NO + (half << 5) + oo] = sY[bbL][oo];
    }
}

// Reduce: spl_reg[q] = (sum_chunk part[chunk][q]) / 2048 / (t9 - t0 + 1e-5)
// 256 blocks x 256 threads: block owns 16 q columns, 16 threads per column
// each sum 16 chunks.
__global__ __launch_bounds__(256) void kan_reduce(
    const float* __restrict__ regpart, const float* __restrict__ grid,
    float* __restrict__ outreg)
{
    __shared__ float sR[16][17];
    const int t  = threadIdx.x;
    const int qo = t & 15, gs = t >> 4;
    const int q  = blockIdx.x * 16 + qo;
    float s = 0.0f;
#pragma unroll
    for (int g = gs * 16; g < gs * 16 + 16; ++g) s += regpart[g * NTOTAL + q];
    sR[gs][qo] = s;
    __syncthreads();
    if (t < 16) {
        float tot = 0.0f;
#pragma unroll
        for (int g2 = 0; g2 < 16; ++g2) tot += sR[g2][t];
        const int jq = blockIdx.x * 16 + t;
        const float norm = grid[jq * 10 + 9] - grid[jq * 10] + 1e-5f;
        outreg[jq] = (tot * (1.0f / (float)BATCHN)) / norm;
    }
}

// Fallback (ws too small): round-3 standalone spl_reg kernel (known-good).
__global__ __launch_bounds__(256) void kan_reg_standalone(
    const float* __restrict__ x, const float* __restrict__ cb,
    const float* __restrict__ grid, float* __restrict__ outreg)
{
    __shared__ float sB2[6][256];
    __shared__ float sR[256];
    const int t = threadIdx.x;
    const int i = blockIdx.x;

    float tt[10];
#pragma unroll
    for (int m = 0; m < 10; ++m) tt[m] = grid[m];
    float inv1[9], inv2[8], inv3[7];
#pragma unroll
    for (int m = 0; m < 9; ++m) inv1[m] = 1.0f / (tt[m + 1] - tt[m]);
#pragma unroll
    for (int m = 0; m < 8; ++m) inv2[m] = 1.0f / (tt[m + 2] - tt[m]);
#pragma unroll
    for (int m = 0; m < 7; ++m) inv3[m] = 1.0f / (tt[m + 3] - tt[m]);

    const int o = t >> 2;
    const int q = t & 3;
    const int j = o * NI + i;
    const float c0 = cb[j * 6 + 0], c1 = cb[j * 6 + 1], c2 = cb[j * 6 + 2];
    const float c3 = cb[j * 6 + 3], c4 = cb[j * 6 + 4], c5 = cb[j * 6 + 5];

    float acc = 0.0f;
    for (int tile = 0; tile < 8; ++tile) {
        const float xv = x[(tile * 256 + t) * NI + i];
        float bo[6], sl;
        eval_basis6(xv, tt, inv1, inv2, inv3, bo, &sl);
        __syncthreads();
#pragma unroll
        for (int m = 0; m < 6; ++m) sB2[m][t] = bo[m];
        __syncthreads();
        for (int bi = 0; bi < 64; ++bi) {
            const int b = q * 64 + ((bi + q * 8) & 63);
            float s = c0 * sB2[0][b];
            s = fmaf(c1, sB2[1][b], s);
            s = fmaf(c2, sB2[2][b], s);
            s = fmaf(c3, sB2[3][b], s);
            s = fmaf(c4, sB2[4][b], s);
            s = fmaf(c5, sB2[5][b], s);
            acc += fabsf(s);
        }
    }
    sR[t] = acc;
    __syncthreads();
    if (t < 64) {
        const float s = sR[t * 4 + 0] + sR[t * 4 + 1] + sR[t * 4 + 2] + sR[t * 4 + 3];
        const int jj = t * NI + i;
        const float norm = grid[jj * 10 + 9] - grid[jj * 10] + 1e-5f;
        outreg[jj] = (s * (1.0f / (float)BATCHN)) / norm;
    }
}

extern "C" void kernel_launch(void* const* d_in, const int* in_sizes, int n_in,
                              void* d_out, int out_size, void* d_ws, size_t ws_size,
                              hipStream_t stream) {
    (void)in_sizes; (void)n_in; (void)out_size;
    const float* x    = (const float*)d_in[0];
    const float* cb   = (const float*)d_in[1];
    const float* cspl = (const float*)d_in[2];
    const float* cres = (const float*)d_in[3];
    const float* grid = (const float*)d_in[4];
    float* y      = (float*)d_out;
    float* outreg = y + BATCHN * NO;

    const size_t needed = (size_t)NCHUNK * NTOTAL * sizeof(float);   // 4 MiB
    if (ws_size >= needed) {
        float* part = (float*)d_ws;
        kan_main<<<NCHUNK * 2, TPB, 0, stream>>>(x, cb, cspl, cres, grid, y, part, 1);
        kan_reduce<<<NTOTAL / 16, 256, 0, stream>>>(part, grid, outreg);
    } else {
        kan_main<<<NCHUNK * 2, TPB, 0, stream>>>(x, cb, cspl, cres, grid, y,
                                                 (float*)d_ws, 0);
        kan_reg_standalone<<<NI, 256, 0, stream>>>(x, cb, grid, outreg);
    }
}